// Round 10
// baseline (464.393 us; speedup 1.0000x reference)
//
#include <hip/hip_runtime.h>

#define HID 64
#define VOC 64
#define NSLOT 8
#define NB 256
#define SEQL 2048
#define NT 512            // 8 waves; wave w computes vocab rows w*8..w*8+7
#define HPAD 65           // hlds pitch: conflict-free

// ---------------------------------------------------------------------------
// memset(4B) + single kernel, 256 blocks x 512 threads (1 block/CU).
// Redundant per-block vocab table in the UNTESTED fast quadrant:
//   - weights staged ONCE per block into LDS with coalesced float4 loads
//     (r7-proven: FETCH stays ~1.6MB; r9's per-wave global streaming caused
//     a 216MB HBM storm);
//   - broadcasts via fully-unrolled __shfl(x, CONST) -> v_readlane, SGPR
//     result, no lgkmcnt (r7's runtime-index bpermute serialized on
//     lgkmcnt(0) ~1.5K times);
//   - weight ds_reads are per-lane consecutive (2-way bank alias = free),
//     independent addresses -> pipelined by the compiler;
//   - 8 rows per wave: each LDS weight read feeds 16 FMAs.
// Then: histogram (overlapped, LDS atomics) -> rank -> greedy top-8
// multiset -> attention -> entropy gate -> logits. Entropy mean: one
// memory-side atomicAdd per block into out[16384], zeroed by the 4B memset
// node (r4-proven; no fences, no flags, no spins -- every cross-block sync
// flavor cost 30-400us on the non-coherent-XCD part).
// ---------------------------------------------------------------------------
__global__ __launch_bounds__(NT) void fused_kernel(
    const int* __restrict__ seq,
    const float* __restrict__ embed, const float* __restrict__ w1, const float* __restrict__ b1,
    const float* __restrict__ w2, const float* __restrict__ b2,
    const float* __restrict__ ln_g, const float* __restrict__ ln_b,
    const float* __restrict__ gate_w, const float* __restrict__ gate_b,
    const float* __restrict__ q_w, const float* __restrict__ q_b,
    const float* __restrict__ out_w, const float* __restrict__ out_b,
    float* __restrict__ out, float* __restrict__ ent_out)
{
    __shared__ float sw1[2 * HID * HID];   // 32 KB: w1[i][j] at i*128+j
    __shared__ float sw2[2 * HID * HID];   // 32 KB: w2[j][i] at j*64+i
    __shared__ float hlds[VOC * HPAD];     // 16.6 KB: h rows, padded
    __shared__ float sscore[VOC];
    __shared__ int   sorder[VOC];
    __shared__ int   hist[VOC];
    __shared__ float sqv[HID];
    __shared__ float sctx[HID];
    __shared__ int   svids[NSLOT];
    __shared__ float sla[NSLOT];
    __shared__ float seff[NSLOT];
    __shared__ int   shvlast;

    const int t = threadIdx.x;
    const int b = blockIdx.x;
    const int lane = t & 63;
    const int wave = t >> 6;

    // Own seq row: 2048 ints = 512 int4, one per thread.
    const int4 a = ((const int4*)(seq + (size_t)b * SEQL))[t];
    if (t < VOC) hist[t] = 0;
    if (t == NT - 1) shvlast = a.w;        // seq[b][2047]

    // Stage w1/w2 into LDS (float4, coalesced, once per block).
    for (int p = t; p < 2 * HID * HID / 4; p += NT)
        ((float4*)sw1)[p] = ((const float4*)w1)[p];
    for (int p = t; p < 2 * HID * HID / 4; p += NT)
        ((float4*)sw2)[p] = ((const float4*)w2)[p];
    __syncthreads();

    // Histogram (LDS atomics; overlaps the FFN below -- no barrier between).
    atomicAdd(&hist[a.x], 1);
    atomicAdd(&hist[a.y], 1);
    atomicAdd(&hist[a.z], 1);
    atomicAdd(&hist[a.w], 1);

    // ---- redundant vocab table: wave computes rows r0..r0+7 ---------------
    {
        const int r0 = wave * 8;
        float e[8];
#pragma unroll
        for (int r = 0; r < 8; ++r) e[r] = embed[(r0 + r) * HID + lane];

        // FFN1: lane = hidden units (lane, lane+64); 8 rows share weights.
        float fa[8], fb[8];
        const float b1a = b1[lane], b1b = b1[HID + lane];
#pragma unroll
        for (int r = 0; r < 8; ++r) { fa[r] = b1a; fb[r] = b1b; }
#pragma unroll
        for (int i = 0; i < HID; ++i) {                // FULL unroll
            const float wa = sw1[i * 2 * HID + lane];
            const float wb = sw1[i * 2 * HID + HID + lane];
#pragma unroll
            for (int r = 0; r < 8; ++r) {
                const float ei = __shfl(e[r], i);      // const -> v_readlane
                fa[r] = fmaf(ei, wa, fa[r]);
                fb[r] = fmaf(ei, wb, fb[r]);
            }
        }
#pragma unroll
        for (int r = 0; r < 8; ++r) {
            fa[r] = fmaxf(fa[r], 0.0f);
            fb[r] = fmaxf(fb[r], 0.0f);
        }

        // FFN2 + residual: lane = output unit i.
        float z[8];
        const float b2v = b2[lane];
#pragma unroll
        for (int r = 0; r < 8; ++r) z[r] = e[r] + b2v;
#pragma unroll
        for (int j = 0; j < HID; ++j) {                // FULL unroll
            const float wva = sw2[j * HID + lane];
            const float wvb = sw2[(HID + j) * HID + lane];
#pragma unroll
            for (int r = 0; r < 8; ++r) {
                z[r] = fmaf(__shfl(fa[r], j), wva, z[r]);
                z[r] = fmaf(__shfl(fb[r], j), wvb, z[r]);
            }
        }

        // LayerNorm + gate score per row (wave butterflies).
        const float lng = ln_g[lane], lnb = ln_b[lane], gwv = gate_w[lane];
        const float gbv = gate_b[0];
#pragma unroll
        for (int r = 0; r < 8; ++r) {
            float s = z[r];
#pragma unroll
            for (int m = 32; m; m >>= 1) s += __shfl_xor(s, m);
            const float mu = s * (1.0f / HID);
            const float d = z[r] - mu;
            float vs = d * d;
#pragma unroll
            for (int m = 32; m; m >>= 1) vs += __shfl_xor(vs, m);
            const float inv = 1.0f / sqrtf(vs * (1.0f / HID) + 1e-5f);
            const float h = d * inv * lng + lnb;
            hlds[(r0 + r) * HPAD + lane] = h;
            float sc = h * gwv;
#pragma unroll
            for (int m = 32; m; m >>= 1) sc += __shfl_xor(sc, m);
            if (lane == 0) sscore[r0 + r] = sc + gbv;
        }
    }
    __syncthreads();                        // h, scores, histogram all ready

    // ---- rank ids (t<64) ; q row of own last token (t in [64,128)) --------
    if (t < VOC) {
        const float sv = sscore[t];
        int r = 0;
        for (int u = 0; u < VOC; ++u) {
            const float su = sscore[u];
            if (su > sv || (su == sv && u < t)) ++r;
        }
        sorder[r] = t;
    } else if (t < 2 * VOC) {
        const int i = t - VOC;
        const int vl = shvlast;
        float qa = q_b[i];
#pragma unroll 8
        for (int k = 0; k < HID; ++k)       // coalesced across lanes per k
            qa = fmaf(hlds[vl * HPAD + k], q_w[k * HID + i], qa);
        sqv[i] = qa;
    }
    __syncthreads();

    // ---- greedy top-8 multiset by descending score with multiplicity ------
    if (t == 0) {
        int r = NSLOT, n = 0, pos = 0;
        while (r > 0) {
            const int v = sorder[pos++];
            int c = hist[v];
            if (c > r) c = r;
            for (int k = 0; k < c; ++k) svids[n++] = v;
            r -= c;
        }
    }
    __syncthreads();

    // ---- attention logits: 8 lanes per slot, 3-step shfl reduce -----------
    if (t < VOC) {
        const int k = t >> 3, e2 = t & 7;
        const float* hr = &hlds[svids[k] * HPAD];
        float p = 0.0f;
#pragma unroll
        for (int m = 0; m < 8; ++m)
            p = fmaf(hr[e2 + 8 * m], sqv[e2 + 8 * m], p);
        p += __shfl_xor(p, 1);
        p += __shfl_xor(p, 2);
        p += __shfl_xor(p, 4);
        if (e2 == 0) sla[k] = p * 0.125f;   // 1/sqrt(64)
    }
    __syncthreads();

    // ---- softmax + entropy gate; memory-side atomicAdd for the mean -------
    if (t == 0) {
        float m = -1e30f;
        for (int k = 0; k < NSLOT; ++k) m = fmaxf(m, sla[k]);
        float e2[NSLOT], s = 0.0f;
        for (int k = 0; k < NSLOT; ++k) { e2[k] = expf(sla[k] - m); s += e2[k]; }
        const float invs = 1.0f / s;
        float ent = 0.0f;
        for (int k = 0; k < NSLOT; ++k) {
            const float av = e2[k] * invs;
            ent -= av * logf(av + 1e-9f);
        }
        const float high = (ent > 1.5f) ? 1.0f : 0.0f;
        for (int k = 0; k < NSLOT; ++k)
            seff[k] = (1.0f - high) * (e2[k] * invs) + high * (1.0f / NSLOT);
        atomicAdd(ent_out, ent * (1.0f / NB));
    }
    __syncthreads();

    // ---- ctx then logits --------------------------------------------------
    if (t < HID) {
        float cx = 0.0f;
#pragma unroll
        for (int k = 0; k < NSLOT; ++k)
            cx = fmaf(seff[k], hlds[svids[k] * HPAD + t], cx);
        sctx[t] = cx;
    }
    __syncthreads();
    if (t < VOC) {
        float o = out_b[t];
#pragma unroll 8
        for (int i = 0; i < HID; ++i)
            o = fmaf(sctx[i], out_w[i * VOC + t], o);
        out[(size_t)b * VOC + t] = o;
    }
}

extern "C" void kernel_launch(void* const* d_in, const int* in_sizes, int n_in,
                              void* d_out, int out_size, void* d_ws, size_t ws_size,
                              hipStream_t stream) {
    const int*   seq    = (const int*)  d_in[0];
    const float* embed  = (const float*)d_in[1];
    const float* w1     = (const float*)d_in[2];
    const float* b1     = (const float*)d_in[3];
    const float* w2     = (const float*)d_in[4];
    const float* b2     = (const float*)d_in[5];
    const float* ln_g   = (const float*)d_in[6];
    const float* ln_b   = (const float*)d_in[7];
    const float* gate_w = (const float*)d_in[8];
    const float* gate_b = (const float*)d_in[9];
    const float* q_w    = (const float*)d_in[10];
    const float* q_b    = (const float*)d_in[11];
    const float* out_w  = (const float*)d_in[12];
    const float* out_b  = (const float*)d_in[13];
    float* out = (float*)d_out;
    float* ent_out = out + (size_t)NB * VOC;

    hipMemsetAsync(ent_out, 0, sizeof(float), stream);
    fused_kernel<<<NB, NT, 0, stream>>>(seq, embed, w1, b1, w2, b2,
                                        ln_g, ln_b, gate_w, gate_b,
                                        q_w, q_b, out_w, out_b,
                                        out, ent_out);
}

// Round 11
// 320.891 us; speedup vs baseline: 1.4472x; 1.4472x over previous
//
#include <hip/hip_runtime.h>

#define HID 64
#define VOC 64
#define NSLOT 8
#define NB 256
#define SEQL 2048
#define NT 512            // 8 waves; wave w computes vocab rows w*8..w*8+7
#define HPAD 65           // hlds pitch: conflict-free

// ---------------------------------------------------------------------------
// memset(4B) + single kernel, 256 blocks x 512 threads (1 block/CU).
// r10 structure with the SPILL FIXED (r9/r10 root cause: WRITE_SIZE=408MB
// scratch traffic from VGPR cap 128 < demand; spills also thrashed L2 and
// caused the 200+MB weight re-fetch):
//   - __launch_bounds__(512, 2): 2 waves/EU -> 256 VGPR budget (we are
//     1 block/CU anyway: 84KB LDS);
//   - 4 rows/wave x 2 sequential passes: live state e[4]/fa[4]/fb[4]/z[4]
//     = 16 array regs instead of 32; pass loop NOT unrolled (17KB code).
// Proven pieces kept: LDS-staged weights (float4), const-lane __shfl
// (v_readlane, no lgkmcnt), histogram overlap, rank/greedy/attention/gate,
// entropy mean = one memory-side atomicAdd per block into out[16384]
// (zeroed by the 4B memset node; no fences/flags -- those cost 30-400us).
// ---------------------------------------------------------------------------
__global__ __launch_bounds__(NT, 2) void fused_kernel(
    const int* __restrict__ seq,
    const float* __restrict__ embed, const float* __restrict__ w1, const float* __restrict__ b1,
    const float* __restrict__ w2, const float* __restrict__ b2,
    const float* __restrict__ ln_g, const float* __restrict__ ln_b,
    const float* __restrict__ gate_w, const float* __restrict__ gate_b,
    const float* __restrict__ q_w, const float* __restrict__ q_b,
    const float* __restrict__ out_w, const float* __restrict__ out_b,
    float* __restrict__ out, float* __restrict__ ent_out)
{
    __shared__ float sw1[2 * HID * HID];   // 32 KB: w1[i][j] at i*128+j
    __shared__ float sw2[2 * HID * HID];   // 32 KB: w2[j][i] at j*64+i
    __shared__ float hlds[VOC * HPAD];     // 16.6 KB: h rows, padded
    __shared__ float sscore[VOC];
    __shared__ int   sorder[VOC];
    __shared__ int   hist[VOC];
    __shared__ float sqv[HID];
    __shared__ float sctx[HID];
    __shared__ int   svids[NSLOT];
    __shared__ float sla[NSLOT];
    __shared__ float seff[NSLOT];
    __shared__ int   shvlast;

    const int t = threadIdx.x;
    const int b = blockIdx.x;
    const int lane = t & 63;
    const int wave = t >> 6;

    // Own seq row: 2048 ints = 512 int4, one per thread.
    const int4 a = ((const int4*)(seq + (size_t)b * SEQL))[t];
    if (t < VOC) hist[t] = 0;
    if (t == NT - 1) shvlast = a.w;        // seq[b][2047]

    // Stage w1/w2 into LDS (float4, coalesced, once per block).
    for (int p = t; p < 2 * HID * HID / 4; p += NT)
        ((float4*)sw1)[p] = ((const float4*)w1)[p];
    for (int p = t; p < 2 * HID * HID / 4; p += NT)
        ((float4*)sw2)[p] = ((const float4*)w2)[p];
    __syncthreads();

    // Histogram (LDS atomics; overlaps the FFN below -- no barrier between).
    atomicAdd(&hist[a.x], 1);
    atomicAdd(&hist[a.y], 1);
    atomicAdd(&hist[a.z], 1);
    atomicAdd(&hist[a.w], 1);

    // ---- redundant vocab table: 2 passes x 4 rows per wave ----------------
    {
        const float b1a = b1[lane], b1b = b1[HID + lane];
        const float b2v = b2[lane];
        const float lng = ln_g[lane], lnb = ln_b[lane], gwv = gate_w[lane];
        const float gbv = gate_b[0];

#pragma unroll 1                            // runtime loop: small code, low VGPR
        for (int pass = 0; pass < 2; ++pass) {
            const int r0 = wave * 8 + pass * 4;

            float e[4];
#pragma unroll
            for (int r = 0; r < 4; ++r) e[r] = embed[(r0 + r) * HID + lane];

            // FFN1: lane = hidden units (lane, lane+64); 4 rows share weights.
            float fa[4], fb[4];
#pragma unroll
            for (int r = 0; r < 4; ++r) { fa[r] = b1a; fb[r] = b1b; }
#pragma unroll
            for (int i = 0; i < HID; ++i) {            // FULL unroll
                const float wa = sw1[i * 2 * HID + lane];
                const float wb = sw1[i * 2 * HID + HID + lane];
#pragma unroll
                for (int r = 0; r < 4; ++r) {
                    const float ei = __shfl(e[r], i);  // const -> v_readlane
                    fa[r] = fmaf(ei, wa, fa[r]);
                    fb[r] = fmaf(ei, wb, fb[r]);
                }
            }
#pragma unroll
            for (int r = 0; r < 4; ++r) {
                fa[r] = fmaxf(fa[r], 0.0f);
                fb[r] = fmaxf(fb[r], 0.0f);
            }

            // FFN2 + residual: lane = output unit i.
            float z[4];
#pragma unroll
            for (int r = 0; r < 4; ++r) z[r] = e[r] + b2v;
#pragma unroll
            for (int j = 0; j < HID; ++j) {            // FULL unroll
                const float wva = sw2[j * HID + lane];
                const float wvb = sw2[(HID + j) * HID + lane];
#pragma unroll
                for (int r = 0; r < 4; ++r) {
                    z[r] = fmaf(__shfl(fa[r], j), wva, z[r]);
                    z[r] = fmaf(__shfl(fb[r], j), wvb, z[r]);
                }
            }

            // LayerNorm + gate score per row (wave butterflies).
#pragma unroll
            for (int r = 0; r < 4; ++r) {
                float s = z[r];
#pragma unroll
                for (int m = 32; m; m >>= 1) s += __shfl_xor(s, m);
                const float mu = s * (1.0f / HID);
                const float d = z[r] - mu;
                float vs = d * d;
#pragma unroll
                for (int m = 32; m; m >>= 1) vs += __shfl_xor(vs, m);
                const float inv = 1.0f / sqrtf(vs * (1.0f / HID) + 1e-5f);
                const float h = d * inv * lng + lnb;
                hlds[(r0 + r) * HPAD + lane] = h;
                float sc = h * gwv;
#pragma unroll
                for (int m = 32; m; m >>= 1) sc += __shfl_xor(sc, m);
                if (lane == 0) sscore[r0 + r] = sc + gbv;
            }
        }
    }
    __syncthreads();                        // h, scores, histogram all ready

    // ---- rank ids (t<64) ; q row of own last token (t in [64,128)) --------
    if (t < VOC) {
        const float sv = sscore[t];
        int r = 0;
        for (int u = 0; u < VOC; ++u) {
            const float su = sscore[u];
            if (su > sv || (su == sv && u < t)) ++r;
        }
        sorder[r] = t;
    } else if (t < 2 * VOC) {
        const int i = t - VOC;
        const int vl = shvlast;
        float qa = q_b[i];
#pragma unroll 8
        for (int k = 0; k < HID; ++k)       // hlds broadcast + coalesced q_w
            qa = fmaf(hlds[vl * HPAD + k], q_w[k * HID + i], qa);
        sqv[i] = qa;
    }
    __syncthreads();

    // ---- greedy top-8 multiset by descending score with multiplicity ------
    if (t == 0) {
        int r = NSLOT, n = 0, pos = 0;
        while (r > 0) {
            const int v = sorder[pos++];
            int c = hist[v];
            if (c > r) c = r;
            for (int k = 0; k < c; ++k) svids[n++] = v;
            r -= c;
        }
    }
    __syncthreads();

    // ---- attention logits: 8 lanes per slot, 3-step shfl reduce -----------
    if (t < VOC) {
        const int k = t >> 3, e2 = t & 7;
        const float* hr = &hlds[svids[k] * HPAD];
        float p = 0.0f;
#pragma unroll
        for (int m = 0; m < 8; ++m)
            p = fmaf(hr[e2 + 8 * m], sqv[e2 + 8 * m], p);
        p += __shfl_xor(p, 1);
        p += __shfl_xor(p, 2);
        p += __shfl_xor(p, 4);
        if (e2 == 0) sla[k] = p * 0.125f;   // 1/sqrt(64)
    }
    __syncthreads();

    // ---- softmax + entropy gate; memory-side atomicAdd for the mean -------
    if (t == 0) {
        float m = -1e30f;
        for (int k = 0; k < NSLOT; ++k) m = fmaxf(m, sla[k]);
        float e2[NSLOT], s = 0.0f;
        for (int k = 0; k < NSLOT; ++k) { e2[k] = expf(sla[k] - m); s += e2[k]; }
        const float invs = 1.0f / s;
        float ent = 0.0f;
        for (int k = 0; k < NSLOT; ++k) {
            const float av = e2[k] * invs;
            ent -= av * logf(av + 1e-9f);
        }
        const float high = (ent > 1.5f) ? 1.0f : 0.0f;
        for (int k = 0; k < NSLOT; ++k)
            seff[k] = (1.0f - high) * (e2[k] * invs) + high * (1.0f / NSLOT);
        atomicAdd(ent_out, ent * (1.0f / NB));
    }
    __syncthreads();

    // ---- ctx then logits --------------------------------------------------
    if (t < HID) {
        float cx = 0.0f;
#pragma unroll
        for (int k = 0; k < NSLOT; ++k)
            cx = fmaf(seff[k], hlds[svids[k] * HPAD + t], cx);
        sctx[t] = cx;
    }
    __syncthreads();
    if (t < VOC) {
        float o = out_b[t];
#pragma unroll 8
        for (int i = 0; i < HID; ++i)
            o = fmaf(sctx[i], out_w[i * VOC + t], o);
        out[(size_t)b * VOC + t] = o;
    }
}

extern "C" void kernel_launch(void* const* d_in, const int* in_sizes, int n_in,
                              void* d_out, int out_size, void* d_ws, size_t ws_size,
                              hipStream_t stream) {
    const int*   seq    = (const int*)  d_in[0];
    const float* embed  = (const float*)d_in[1];
    const float* w1     = (const float*)d_in[2];
    const float* b1     = (const float*)d_in[3];
    const float* w2     = (const float*)d_in[4];
    const float* b2     = (const float*)d_in[5];
    const float* ln_g   = (const float*)d_in[6];
    const float* ln_b   = (const float*)d_in[7];
    const float* gate_w = (const float*)d_in[8];
    const float* gate_b = (const float*)d_in[9];
    const float* q_w    = (const float*)d_in[10];
    const float* q_b    = (const float*)d_in[11];
    const float* out_w  = (const float*)d_in[12];
    const float* out_b  = (const float*)d_in[13];
    float* out = (float*)d_out;
    float* ent_out = out + (size_t)NB * VOC;

    hipMemsetAsync(ent_out, 0, sizeof(float), stream);
    fused_kernel<<<NB, NT, 0, stream>>>(seq, embed, w1, b1, w2, b2,
                                        ln_g, ln_b, gate_w, gate_b,
                                        q_w, q_b, out_w, out_b,
                                        out, ent_out);
}

// Round 12
// 36.876 us; speedup vs baseline: 12.5935x; 8.7020x over previous
//
#include <hip/hip_runtime.h>

#define HID 64
#define VOC 64
#define NSLOT 8
#define NB 256
#define SEQL 2048
#define NT 512            // 8 waves
#define EPAD 65           // semb pitch (odd): per-lane stride reads 2-way = free
#define FPAD 129          // sff  pitch (odd): per-lane stride reads 2-way = free

// ---------------------------------------------------------------------------
// memset(4B) + single kernel, 256 blocks x 512 threads (1 block/CU, 114KB LDS).
// Redundant per-block vocab table with ZERO cross-lane broadcasts in the hot
// loops (r9/r10/r11 post-mortem: full unroll + shfl-const -> scheduler hoists
// everything -> spill storm (WRITE 356-408MB); partial unroll + shfl-runtime
// -> ds_bpermute serialization (r7); wave-uniform GLOBAL loads -> s_load
// lgkmcnt drains (r5/r6)). New layout: lane = vocab row, wave = output-unit
// slice:
//   FFN1: lane v, wave w accumulates acc[16] for j in [w*16,w*16+16):
//         ev = semb[v*65+i]   per-lane ds_read, free;
//         w1 row slice        wave-uniform ds_read_b128 x4 (HW broadcast,
//                             in-order DS returns, fine-grained lgkmcnt);
//         NO shfl, NO s_load, partial unroll safe -> ~45 live VGPR, no spill.
//   FFN2: same shape, acc[8] for i in [w*8,w*8+8), z = e + ffn in-place.
//   LN+score: wave handles 8 rows, lane = element, const-mask shfl_xor
//         butterflies (DPP, proven in r2/r4).
// Downstream (histogram/rank/greedy/attention/gate/logits) = r10's proven
// tail. Entropy mean: one memory-side atomicAdd per block into out[16384],
// zeroed by the 4B memset node (r4-proven; all fence/flag schemes cost
// 30-400us on the non-coherent-XCD part).
// ---------------------------------------------------------------------------
__global__ __launch_bounds__(NT) void fused_kernel(
    const int* __restrict__ seq,
    const float* __restrict__ embed, const float* __restrict__ w1, const float* __restrict__ b1,
    const float* __restrict__ w2, const float* __restrict__ b2,
    const float* __restrict__ ln_g, const float* __restrict__ ln_b,
    const float* __restrict__ gate_w, const float* __restrict__ gate_b,
    const float* __restrict__ q_w, const float* __restrict__ q_b,
    const float* __restrict__ out_w, const float* __restrict__ out_b,
    float* __restrict__ out, float* __restrict__ ent_out)
{
    __shared__ float sw1[2 * HID * HID];   // 32 KB: w1[i][j] at i*128+j
    __shared__ float sw2[2 * HID * HID];   // 32 KB: w2[j][i] at j*64+i
    __shared__ float semb[VOC * EPAD];     // 16.6 KB: embed rows; z in place
    __shared__ float sff[VOC * FPAD];      // 33 KB: ff1 rows; h in place
    __shared__ float sscore[VOC];
    __shared__ int   sorder[VOC];
    __shared__ int   hist[VOC];
    __shared__ float sqv[HID];
    __shared__ float sctx[HID];
    __shared__ int   svids[NSLOT];
    __shared__ float sla[NSLOT];
    __shared__ float seff[NSLOT];
    __shared__ int   shvlast;

    const int t = threadIdx.x;
    const int b = blockIdx.x;
    const int lane = t & 63;
    const int wave = t >> 6;

    // Own seq row: 2048 ints = 512 int4, one per thread (issued first).
    const int4 a = ((const int4*)(seq + (size_t)b * SEQL))[t];
    if (t < VOC) hist[t] = 0;
    if (t == NT - 1) shvlast = a.w;        // seq[b][2047]

    // Stage w1/w2 (float4 -> b128 LDS) and embed (scalar writes, odd pitch).
    for (int p = t; p < 2 * HID * HID / 4; p += NT)
        ((float4*)sw1)[p] = ((const float4*)w1)[p];
    for (int p = t; p < 2 * HID * HID / 4; p += NT)
        ((float4*)sw2)[p] = ((const float4*)w2)[p];
    for (int p = t; p < VOC * HID / 4; p += NT) {
        const float4 v = ((const float4*)embed)[p];
        const int r = (p * 4) >> 6, c = (p * 4) & 63;
        float* dst = &semb[r * EPAD + c];
        dst[0] = v.x; dst[1] = v.y; dst[2] = v.z; dst[3] = v.w;
    }
    __syncthreads();

    // Histogram (LDS atomics; overlaps FFN1 below).
    atomicAdd(&hist[a.x], 1);
    atomicAdd(&hist[a.y], 1);
    atomicAdd(&hist[a.z], 1);
    atomicAdd(&hist[a.w], 1);

    // ---- FFN1: lane = vocab row v, wave covers j in [wave*16, +16) --------
    {
        const int jb = wave * 16;
        float acc[16];
#pragma unroll
        for (int jj = 0; jj < 16; ++jj) acc[jj] = b1[jb + jj];
#pragma unroll 2
        for (int i = 0; i < HID; ++i) {
            const float ev = semb[lane * EPAD + i];            // per-lane, free
            const float4 wq0 = *(const float4*)&sw1[i * 2 * HID + jb];      // uniform b128
            const float4 wq1 = *(const float4*)&sw1[i * 2 * HID + jb + 4];
            const float4 wq2 = *(const float4*)&sw1[i * 2 * HID + jb + 8];
            const float4 wq3 = *(const float4*)&sw1[i * 2 * HID + jb + 12];
            acc[0]  = fmaf(ev, wq0.x, acc[0]);  acc[1]  = fmaf(ev, wq0.y, acc[1]);
            acc[2]  = fmaf(ev, wq0.z, acc[2]);  acc[3]  = fmaf(ev, wq0.w, acc[3]);
            acc[4]  = fmaf(ev, wq1.x, acc[4]);  acc[5]  = fmaf(ev, wq1.y, acc[5]);
            acc[6]  = fmaf(ev, wq1.z, acc[6]);  acc[7]  = fmaf(ev, wq1.w, acc[7]);
            acc[8]  = fmaf(ev, wq2.x, acc[8]);  acc[9]  = fmaf(ev, wq2.y, acc[9]);
            acc[10] = fmaf(ev, wq2.z, acc[10]); acc[11] = fmaf(ev, wq2.w, acc[11]);
            acc[12] = fmaf(ev, wq3.x, acc[12]); acc[13] = fmaf(ev, wq3.y, acc[13]);
            acc[14] = fmaf(ev, wq3.z, acc[14]); acc[15] = fmaf(ev, wq3.w, acc[15]);
        }
#pragma unroll
        for (int jj = 0; jj < 16; ++jj)        // b32 writes, stride FPAD: free
            sff[lane * FPAD + jb + jj] = fmaxf(acc[jj], 0.0f);
    }
    __syncthreads();

    // ---- FFN2 + residual: lane = row v, wave covers i in [wave*8, +8) -----
    {
        const int ib = wave * 8;
        float acc[8];
#pragma unroll
        for (int ii = 0; ii < 8; ++ii) acc[ii] = b2[ib + ii];
#pragma unroll 2
        for (int j = 0; j < 2 * HID; ++j) {
            const float fv = sff[lane * FPAD + j];             // per-lane, free
            const float4 wq0 = *(const float4*)&sw2[j * HID + ib];          // uniform b128
            const float4 wq1 = *(const float4*)&sw2[j * HID + ib + 4];
            acc[0] = fmaf(fv, wq0.x, acc[0]); acc[1] = fmaf(fv, wq0.y, acc[1]);
            acc[2] = fmaf(fv, wq0.z, acc[2]); acc[3] = fmaf(fv, wq0.w, acc[3]);
            acc[4] = fmaf(fv, wq1.x, acc[4]); acc[5] = fmaf(fv, wq1.y, acc[5]);
            acc[6] = fmaf(fv, wq1.z, acc[6]); acc[7] = fmaf(fv, wq1.w, acc[7]);
        }
#pragma unroll
        for (int ii = 0; ii < 8; ++ii)         // z = e + ffn, in place
            semb[lane * EPAD + ib + ii] += acc[ii];
    }
    __syncthreads();

    // ---- LayerNorm + gate score: wave handles rows [wave*8, +8) -----------
    {
        const float lng = ln_g[lane], lnb = ln_b[lane], gwv = gate_w[lane];
        const float gbv = gate_b[0];
#pragma unroll 1
        for (int rr = 0; rr < 8; ++rr) {
            const int r = wave * 8 + rr;
            const float z = semb[r * EPAD + lane];
            float s = z;
#pragma unroll
            for (int m = 32; m; m >>= 1) s += __shfl_xor(s, m);
            const float mu = s * (1.0f / HID);
            const float d = z - mu;
            float vs = d * d;
#pragma unroll
            for (int m = 32; m; m >>= 1) vs += __shfl_xor(vs, m);
            const float inv = 1.0f / sqrtf(vs * (1.0f / HID) + 1e-5f);
            const float h = d * inv * lng + lnb;
            sff[r * FPAD + lane] = h;          // h overwrites ff1 row
            float sc = h * gwv;
#pragma unroll
            for (int m = 32; m; m >>= 1) sc += __shfl_xor(sc, m);
            if (lane == 0) sscore[r] = sc + gbv;
        }
    }
    __syncthreads();                           // h, scores, histogram ready

    // ---- rank ids (t<64) ; q row of own last token (t in [64,128)) --------
    if (t < VOC) {
        const float sv = sscore[t];
        int r = 0;
        for (int u = 0; u < VOC; ++u) {
            const float su = sscore[u];
            if (su > sv || (su == sv && u < t)) ++r;
        }
        sorder[r] = t;
    } else if (t < 2 * VOC) {
        const int i = t - VOC;
        const int vl = shvlast;
        float qa = q_b[i];
#pragma unroll 8
        for (int k = 0; k < HID; ++k)          // uniform ds_read + coalesced q_w
            qa = fmaf(sff[vl * FPAD + k], q_w[k * HID + i], qa);
        sqv[i] = qa;
    }
    __syncthreads();

    // ---- greedy top-8 multiset by descending score with multiplicity ------
    if (t == 0) {
        int r = NSLOT, n = 0, pos = 0;
        while (r > 0) {
            const int v = sorder[pos++];
            int c = hist[v];
            if (c > r) c = r;
            for (int k = 0; k < c; ++k) svids[n++] = v;
            r -= c;
        }
    }
    __syncthreads();

    // ---- attention logits: 8 lanes per slot, 3-step shfl reduce -----------
    if (t < VOC) {
        const int k = t >> 3, e2 = t & 7;
        const float* hr = &sff[svids[k] * FPAD];
        float p = 0.0f;
#pragma unroll
        for (int m = 0; m < 8; ++m)
            p = fmaf(hr[e2 + 8 * m], sqv[e2 + 8 * m], p);
        p += __shfl_xor(p, 1);
        p += __shfl_xor(p, 2);
        p += __shfl_xor(p, 4);
        if (e2 == 0) sla[k] = p * 0.125f;      // 1/sqrt(64)
    }
    __syncthreads();

    // ---- softmax + entropy gate; memory-side atomicAdd for the mean -------
    if (t == 0) {
        float m = -1e30f;
        for (int k = 0; k < NSLOT; ++k) m = fmaxf(m, sla[k]);
        float e2[NSLOT], s = 0.0f;
        for (int k = 0; k < NSLOT; ++k) { e2[k] = expf(sla[k] - m); s += e2[k]; }
        const float invs = 1.0f / s;
        float ent = 0.0f;
        for (int k = 0; k < NSLOT; ++k) {
            const float av = e2[k] * invs;
            ent -= av * logf(av + 1e-9f);
        }
        const float high = (ent > 1.5f) ? 1.0f : 0.0f;
        for (int k = 0; k < NSLOT; ++k)
            seff[k] = (1.0f - high) * (e2[k] * invs) + high * (1.0f / NSLOT);
        atomicAdd(ent_out, ent * (1.0f / NB));
    }
    __syncthreads();

    // ---- ctx then logits --------------------------------------------------
    if (t < HID) {
        float cx = 0.0f;
#pragma unroll
        for (int k = 0; k < NSLOT; ++k)
            cx = fmaf(seff[k], sff[svids[k] * FPAD + t], cx);
        sctx[t] = cx;
    }
    __syncthreads();
    if (t < VOC) {
        float o = out_b[t];
#pragma unroll 8
        for (int i = 0; i < HID; ++i)
            o = fmaf(sctx[i], out_w[i * VOC + t], o);
        out[(size_t)b * VOC + t] = o;
    }
}

extern "C" void kernel_launch(void* const* d_in, const int* in_sizes, int n_in,
                              void* d_out, int out_size, void* d_ws, size_t ws_size,
                              hipStream_t stream) {
    const int*   seq    = (const int*)  d_in[0];
    const float* embed  = (const float*)d_in[1];
    const float* w1     = (const float*)d_in[2];
    const float* b1     = (const float*)d_in[3];
    const float* w2     = (const float*)d_in[4];
    const float* b2     = (const float*)d_in[5];
    const float* ln_g   = (const float*)d_in[6];
    const float* ln_b   = (const float*)d_in[7];
    const float* gate_w = (const float*)d_in[8];
    const float* gate_b = (const float*)d_in[9];
    const float* q_w    = (const float*)d_in[10];
    const float* q_b    = (const float*)d_in[11];
    const float* out_w  = (const float*)d_in[12];
    const float* out_b  = (const float*)d_in[13];
    float* out = (float*)d_out;
    float* ent_out = out + (size_t)NB * VOC;

    hipMemsetAsync(ent_out, 0, sizeof(float), stream);
    fused_kernel<<<NB, NT, 0, stream>>>(seq, embed, w1, b1, w2, b2,
                                        ln_g, ln_b, gate_w, gate_b,
                                        q_w, q_b, out_w, out_b,
                                        out, ent_out);
}